// Round 15
// baseline (544.361 us; speedup 1.0000x reference)
//
#include <hip/hip_runtime.h>
#include <math.h>

#define NPTS 16384
#define DIN 13
#define KNN 8
#define GL 12                 // group-list depth
#define BIGF 1.7014118e38f    // 0x7F000000 — finite sentinel, id bits 0

typedef _Float16 half8 __attribute__((ext_vector_type(8)));
typedef float f32x4 __attribute__((ext_vector_type(4)));
typedef float f32x16 __attribute__((ext_vector_type(16)));

__device__ __forceinline__ float silu(float v) {
    return v / (1.0f + __expf(-v));
}

#define MED3(v, a, b) __builtin_amdgcn_fmed3f((v), (a), (b))

#define INS8V(v) {                      \
    d7 = MED3((v), d6, d7);             \
    d6 = MED3((v), d5, d6);             \
    d5 = MED3((v), d4, d5);             \
    d4 = MED3((v), d3, d4);             \
    d3 = MED3((v), d2, d3);             \
    d2 = MED3((v), d1, d2);             \
    d1 = MED3((v), d0, d1);             \
    d0 = fminf((v), d0); }

#define INS12G(v) {                     \
    g11 = MED3((v), g10, g11);          \
    g10 = MED3((v), g9, g10);           \
    g9  = MED3((v), g8, g9);            \
    g8  = MED3((v), g7, g8);            \
    g7  = MED3((v), g6, g7);            \
    g6  = MED3((v), g5, g6);            \
    g5  = MED3((v), g4, g5);            \
    g4  = MED3((v), g3, g4);            \
    g3  = MED3((v), g2, g3);            \
    g2  = MED3((v), g1, g2);            \
    g1  = MED3((v), g0, g1);            \
    g0  = fminf((v), g0); }

#define CSW(p, q) { float lo_ = fminf(m##p, m##q); float hi_ = fmaxf(m##p, m##q); m##p = lo_; m##q = hi_; }

#define CLEAN16() \
    CSW(0,8) CSW(1,9) CSW(2,10) CSW(3,11) CSW(4,12) CSW(5,13) CSW(6,14) CSW(7,15) \
    CSW(0,4) CSW(1,5) CSW(2,6) CSW(3,7) CSW(8,12) CSW(9,13) CSW(10,14) CSW(11,15) \
    CSW(0,2) CSW(1,3) CSW(4,6) CSW(5,7) CSW(8,10) CSW(9,11) CSW(12,14) CSW(13,15) \
    CSW(0,1) CSW(2,3) CSW(4,5) CSW(6,7) CSW(8,9) CSW(10,11) CSW(12,13) CSW(14,15)

#define MERGE12_SHFL(mask) {                                  \
    float b0 = __shfl_xor(g0, (mask), 64);                    \
    float b1 = __shfl_xor(g1, (mask), 64);                    \
    float b2 = __shfl_xor(g2, (mask), 64);                    \
    float b3 = __shfl_xor(g3, (mask), 64);                    \
    float b4 = __shfl_xor(g4, (mask), 64);                    \
    float b5 = __shfl_xor(g5, (mask), 64);                    \
    float b6 = __shfl_xor(g6, (mask), 64);                    \
    float b7 = __shfl_xor(g7, (mask), 64);                    \
    float b8 = __shfl_xor(g8, (mask), 64);                    \
    float b9 = __shfl_xor(g9, (mask), 64);                    \
    float b10 = __shfl_xor(g10, (mask), 64);                  \
    float b11 = __shfl_xor(g11, (mask), 64);                  \
    float m0 = g0, m1 = g1, m2 = g2, m3 = g3;                 \
    float m4 = fminf(g4, b11), m5 = fminf(g5, b10);           \
    float m6 = fminf(g6, b9),  m7 = fminf(g7, b8);            \
    float m8 = fminf(g8, b7),  m9 = fminf(g9, b6);            \
    float m10 = fminf(g10, b5), m11 = fminf(g11, b4);         \
    float m12 = b3, m13 = b2, m14 = b1, m15 = b0;             \
    CLEAN16();                                                \
    g0 = m0; g1 = m1; g2 = m2; g3 = m3; g4 = m4; g5 = m5;     \
    g6 = m6; g7 = m7; g8 = m8; g9 = m9; g10 = m10; g11 = m11; }

#define MERGE12_LDS(LD) {                                     \
    float b0 = LD(0), b1 = LD(1), b2 = LD(2), b3 = LD(3);     \
    float b4 = LD(4), b5 = LD(5), b6 = LD(6), b7 = LD(7);     \
    float b8 = LD(8), b9 = LD(9), b10 = LD(10), b11 = LD(11); \
    float m0 = g0, m1 = g1, m2 = g2, m3 = g3;                 \
    float m4 = fminf(g4, b11), m5 = fminf(g5, b10);           \
    float m6 = fminf(g6, b9),  m7 = fminf(g7, b8);            \
    float m8 = fminf(g8, b7),  m9 = fminf(g9, b6);            \
    float m10 = fminf(g10, b5), m11 = fminf(g11, b4);         \
    float m12 = b3, m13 = b2, m14 = b1, m15 = b0;             \
    CLEAN16();                                                \
    g0 = m0; g1 = m1; g2 = m2; g3 = m3; g4 = m4; g5 = m5;     \
    g6 = m6; g7 = m7; g8 = m8; g9 = m9; g10 = m10; g11 = m11; }

#define MERGE8(mask) {                                   \
    float b0 = __shfl_xor(d0, (mask), 64);               \
    float b1 = __shfl_xor(d1, (mask), 64);               \
    float b2 = __shfl_xor(d2, (mask), 64);               \
    float b3 = __shfl_xor(d3, (mask), 64);               \
    float b4 = __shfl_xor(d4, (mask), 64);               \
    float b5 = __shfl_xor(d5, (mask), 64);               \
    float b6 = __shfl_xor(d6, (mask), 64);               \
    float b7 = __shfl_xor(d7, (mask), 64);               \
    float m0 = fminf(d0, b7), m1 = fminf(d1, b6);        \
    float m2 = fminf(d2, b5), m3 = fminf(d3, b4);        \
    float m4 = fminf(d4, b3), m5 = fminf(d5, b2);        \
    float m6 = fminf(d6, b1), m7 = fminf(d7, b0);        \
    CSW(0,4) CSW(1,5) CSW(2,6) CSW(3,7)                  \
    CSW(0,2) CSW(1,3) CSW(4,6) CSW(5,7)                  \
    CSW(0,1) CSW(2,3) CSW(4,5) CSW(6,7)                  \
    d0 = m0; d1 = m1; d2 = m2; d3 = m3;                  \
    d4 = m4; d5 = m5; d6 = m6; d7 = m7; }

// ---- K1: encoder MLP -> x, H/L/YH/YL f16 splits, SQF, permuted SQP, ACC ----
__global__ __launch_bounds__(64) void k_encoder(
    const float* __restrict__ x_pfc,
    const float* __restrict__ W1, const float* __restrict__ b1,
    const float* __restrict__ W2, const float* __restrict__ b2,
    const float* __restrict__ W3, const float* __restrict__ b3,
    const float* __restrict__ We, const float* __restrict__ be,
    float* __restrict__ xo, _Float16* __restrict__ H, _Float16* __restrict__ L,
    _Float16* __restrict__ YH, _Float16* __restrict__ YL,
    float* __restrict__ SQF, float* __restrict__ SQP, float* __restrict__ ACC)
{
    __shared__ float sW1[DIN * 8];
    __shared__ float sb1[8];
    __shared__ float sW2[8 * 16];
    __shared__ float sb2[16];
    __shared__ float sW3[16 * 15];
    __shared__ float sb3[15];
    __shared__ float sWe[16 * 16];
    __shared__ float sbe[16];
    int t = threadIdx.x;
    for (int q = t; q < DIN * 8; q += 64) sW1[q] = W1[q];
    for (int q = t; q < 8; q += 64) sb1[q] = b1[q];
    for (int q = t; q < 8 * 16; q += 64) sW2[q] = W2[q];
    for (int q = t; q < 16; q += 64) sb2[q] = b2[q];
    for (int q = t; q < 16 * 15; q += 64) sW3[q] = W3[q];
    for (int q = t; q < 15; q += 64) sb3[q] = b3[q];
    for (int q = t; q < 16 * 16; q += 64) sWe[q] = We[q];
    for (int q = t; q < 16; q += 64) sbe[q] = be[q];
    __syncthreads();

    int i = blockIdx.x * 64 + t;
    float in[DIN];
#pragma unroll
    for (int d = 0; d < DIN; ++d) in[d] = x_pfc[i * DIN + d];

    float a1[8];
#pragma unroll
    for (int h = 0; h < 8; ++h) a1[h] = sb1[h];
#pragma unroll
    for (int d = 0; d < DIN; ++d) {
        float v = in[d];
#pragma unroll
        for (int h = 0; h < 8; ++h) a1[h] += v * sW1[d * 8 + h];
    }
#pragma unroll
    for (int h = 0; h < 8; ++h) a1[h] = silu(a1[h]);

    float a2[16];
#pragma unroll
    for (int h = 0; h < 16; ++h) a2[h] = sb2[h];
#pragma unroll
    for (int d = 0; d < 8; ++d) {
        float v = a1[d];
#pragma unroll
        for (int h = 0; h < 16; ++h) a2[h] += v * sW2[d * 16 + h];
    }
#pragma unroll
    for (int h = 0; h < 16; ++h) a2[h] = silu(a2[h]);

    float a3[15];
#pragma unroll
    for (int h = 0; h < 15; ++h) a3[h] = sb3[h];
#pragma unroll
    for (int d = 0; d < 16; ++d) {
        float v = a2[d];
#pragma unroll
        for (int h = 0; h < 15; ++h) a3[h] += v * sW3[d * 15 + h];
    }

    float xr[16];
#pragma unroll
    for (int h = 0; h < 15; ++h) xr[h] = a3[h];
    xr[15] = in[DIN - 1];

    float s = 0.0f;
#pragma unroll
    for (int d = 0; d < 16; ++d) s += xr[d] * xr[d];

    float accb[16];
#pragma unroll
    for (int h = 0; h < 16; ++h) accb[h] = sbe[h];
#pragma unroll
    for (int d = 0; d < 16; ++d) {
        float v = xr[d];
#pragma unroll
        for (int h = 0; h < 16; ++h) accb[h] += v * sWe[d * 16 + h];
    }

    _Float16 hb[16], lb[16], yhb[16], ylb[16];
#pragma unroll
    for (int d = 0; d < 16; ++d) {
        _Float16 h = (_Float16)xr[d];
        hb[d] = h;
        lb[d] = (_Float16)(xr[d] - (float)h);
        float y = -2.0f * xr[d];
        _Float16 yh = (_Float16)y;
        yhb[d] = yh;
        ylb[d] = (_Float16)(y - (float)yh);
    }
    {
        uint4* p;
        p = (uint4*)(H + (size_t)i * 16);  p[0] = ((uint4*)hb)[0];  p[1] = ((uint4*)hb)[1];
        p = (uint4*)(L + (size_t)i * 16);  p[0] = ((uint4*)lb)[0];  p[1] = ((uint4*)lb)[1];
        p = (uint4*)(YH + (size_t)i * 16); p[0] = ((uint4*)yhb)[0]; p[1] = ((uint4*)yhb)[1];
        p = (uint4*)(YL + (size_t)i * 16); p[0] = ((uint4*)ylb)[0]; p[1] = ((uint4*)ylb)[1];
        f32x4* xq = (f32x4*)(xo + (size_t)i * 16);
        f32x4* aq = (f32x4*)(ACC + (size_t)i * 16);
#pragma unroll
        for (int q = 0; q < 4; ++q) {
            f32x4 xv, av;
#pragma unroll
            for (int r = 0; r < 4; ++r) { xv[r] = xr[q * 4 + r]; av[r] = accb[q * 4 + r]; }
            xq[q] = xv;
            aq[q] = av;
        }
    }
    SQF[i] = s;
    {
        int tile = i >> 5;
        int ri = i & 31;
        int hh = (ri >> 2) & 1;
        int r = ((ri >> 3) << 2) | (ri & 3);
        SQP[tile * 32 + hh * 16 + r] = s;
    }
}

// ---- K2: MFMA 32x32 KNN single-pass + ticket-fused head ----
// Grid 1024 = 512 i-tiles x 2 j-halves, 8 waves. knn body = round 12 (group
// -min packed selection, exact-safe). After CV dump: per-i-tile ticket
// (ws poison 0xAA.. is even -> odd old = last). Last block merges both
// halves' 12-lists, re-evaluates 12 groups x 16 j in exact fp32 (registers),
// kth via 16-lane butterfly, then edge conv + head MLP. launch_bounds(512,4)
// -> 128-VGPR cap so the tail cannot spill (round-10 lesson).
__global__ __launch_bounds__(512, 4) void k_knn(
    const _Float16* __restrict__ H, const _Float16* __restrict__ L,
    const _Float16* __restrict__ YH, const _Float16* __restrict__ YL,
    const float* __restrict__ SQP, unsigned* __restrict__ CV,
    unsigned* __restrict__ tickets,
    const float* __restrict__ x, const float* __restrict__ SQF,
    const float* __restrict__ x_pfc, const float* __restrict__ ACC,
    const float* __restrict__ We,
    const float* __restrict__ Wf1, const float* __restrict__ bf1,
    const float* __restrict__ Wf2, const float* __restrict__ bf2,
    float* __restrict__ out)
{
    __shared__ float wl[8 * GL * 32];   // 12 KB
    __shared__ unsigned sOld;
    __shared__ float sWe2[16 * 16];
    __shared__ float sWf1[16 * 32];
    __shared__ float sbf1[32];
    __shared__ float sWf2[32 * 16];
    __shared__ float sbf2[16];
    __shared__ int sGrp[32][GL];
    __shared__ int cnt[32];
    __shared__ int sIdx[32 * 8];

    int t = threadIdx.x;
    int w = t >> 6;
    int lane = t & 63;
    int r31 = lane & 31;
    int hh = lane >> 5;
    int ih = blockIdx.x >> 1;
    int jh = blockIdx.x & 1;
    int i0 = ih * 32;

    int gi = i0 + r31;
    half8 B1 = *(const half8*)(YH + (size_t)gi * 16 + hh * 8);
    half8 B2 = *(const half8*)(YL + (size_t)gi * 16 + hh * 8);

    float g0 = BIGF, g1 = BIGF, g2 = BIGF, g3 = BIGF;
    float g4 = BIGF, g5 = BIGF, g6 = BIGF, g7 = BIGF;
    float g8 = BIGF, g9 = BIGF, g10 = BIGF, g11 = BIGF;

    int jw = jh * 8192 + w * 1024;
    const _Float16* pH = H + ((size_t)(jw + r31)) * 16 + hh * 8;
    const _Float16* pL = L + ((size_t)(jw + r31)) * 16 + hh * 8;
    const float* pS = SQP + jw + hh * 16;
    unsigned idt = (unsigned)((w << 1) | hh);

    for (int tt = 0; tt < 32; ++tt) {
        half8 Ah = *(const half8*)pH;
        half8 Al = *(const half8*)pL;
        f32x16 c = *(const f32x16*)pS;   // sq seeded

        c = __builtin_amdgcn_mfma_f32_32x32x16_f16(Ah, B1, c, 0, 0, 0);
        c = __builtin_amdgcn_mfma_f32_32x32x16_f16(Al, B1, c, 0, 0, 0);
        c = __builtin_amdgcn_mfma_f32_32x32x16_f16(Ah, B2, c, 0, 0, 0);

        float t01 = fminf(c[0], c[1]),  t23 = fminf(c[2], c[3]);
        float t45 = fminf(c[4], c[5]),  t67 = fminf(c[6], c[7]);
        float t89 = fminf(c[8], c[9]),  tAB = fminf(c[10], c[11]);
        float tCD = fminf(c[12], c[13]), tEF = fminf(c[14], c[15]);
        float q0 = fminf(t01, t23), q1 = fminf(t45, t67);
        float q2 = fminf(t89, tAB), q3 = fminf(tCD, tEF);
        float vmin = fminf(fminf(q0, q1), fminf(q2, q3));

        unsigned pk = (__float_as_uint(vmin) & 0xFFFFFC00u) | idt;
        float pf = __uint_as_float(pk);
        INS12G(pf);

        idt += 16;
        pH += 32 * 16;
        pL += 32 * 16;
        pS += 32;
    }

    MERGE12_SHFL(32);

#define STORE12() if (lane < 32) {                     \
        wl[(w * GL + 0) * 32 + r31] = g0;              \
        wl[(w * GL + 1) * 32 + r31] = g1;              \
        wl[(w * GL + 2) * 32 + r31] = g2;              \
        wl[(w * GL + 3) * 32 + r31] = g3;              \
        wl[(w * GL + 4) * 32 + r31] = g4;              \
        wl[(w * GL + 5) * 32 + r31] = g5;              \
        wl[(w * GL + 6) * 32 + r31] = g6;              \
        wl[(w * GL + 7) * 32 + r31] = g7;              \
        wl[(w * GL + 8) * 32 + r31] = g8;              \
        wl[(w * GL + 9) * 32 + r31] = g9;              \
        wl[(w * GL + 10) * 32 + r31] = g10;            \
        wl[(w * GL + 11) * 32 + r31] = g11; }

    if (w >= 4) STORE12();
    __syncthreads();
    if (w < 4) {
        int pw = w + 4;
#define LD(s) wl[(pw * GL + (s)) * 32 + r31]
        MERGE12_LDS(LD);
#undef LD
    }
    __syncthreads();
    if (w == 2 || w == 3) STORE12();
    __syncthreads();
    if (w < 2) {
        int pw = w + 2;
#define LD(s) wl[(pw * GL + (s)) * 32 + r31]
        MERGE12_LDS(LD);
#undef LD
    }
    __syncthreads();
    if (w == 1) STORE12();
    __syncthreads();
    if (w == 0) {
        int pw = 1;
#define LD(s) wl[(pw * GL + (s)) * 32 + r31]
        MERGE12_LDS(LD);
#undef LD
        if (lane < 32) {
            unsigned jb = ((unsigned)jh) << 9;
            size_t base = ((size_t)jh * NPTS + (i0 + r31)) * GL;
            CV[base + 0] = __float_as_uint(g0) | jb;
            CV[base + 1] = __float_as_uint(g1) | jb;
            CV[base + 2] = __float_as_uint(g2) | jb;
            CV[base + 3] = __float_as_uint(g3) | jb;
            CV[base + 4] = __float_as_uint(g4) | jb;
            CV[base + 5] = __float_as_uint(g5) | jb;
            CV[base + 6] = __float_as_uint(g6) | jb;
            CV[base + 7] = __float_as_uint(g7) | jb;
            CV[base + 8] = __float_as_uint(g8) | jb;
            CV[base + 9] = __float_as_uint(g9) | jb;
            CV[base + 10] = __float_as_uint(g10) | jb;
            CV[base + 11] = __float_as_uint(g11) | jb;
        }
    }
#undef STORE12

    // ---- ticket: last block for this i-tile runs the head tail ----
    __threadfence();
    __syncthreads();
    if (t == 0) sOld = atomicAdd(&tickets[ih], 1u);
    __syncthreads();
    if ((sOld & 1u) == 0u) return;   // first arriver (poison is even)
    __threadfence();                 // acquire other half's CV dump

    // stage head weights
    for (int q = t; q < 16 * 16; q += 512) sWe2[q] = We[256 + q];
    for (int q = t; q < 16 * 32; q += 512) sWf1[q] = Wf1[q];
    if (t < 32) sbf1[t] = bf1[t];
    for (int q = t; q < 32 * 16; q += 512) sWf2[q] = Wf2[q];
    if (t < 16) sbf2[t] = bf2[t];
    if (t < 32) cnt[t] = 0;

    // merge both halves' 12-lists -> top-12 group ids (threads 0..31)
    if (t < 32) {
        int ii = i0 + t;
        float g0 = BIGF, g1 = BIGF, g2 = BIGF, g3 = BIGF;
        float g4 = BIGF, g5 = BIGF, g6 = BIGF, g7 = BIGF;
        float g8 = BIGF, g9 = BIGF, g10 = BIGF, g11 = BIGF;
        const unsigned* c0 = CV + (size_t)ii * GL;
        const unsigned* c1 = CV + ((size_t)NPTS + ii) * GL;
#pragma unroll
        for (int s = 0; s < GL; ++s) { float v = __uint_as_float(c0[s]); INS12G(v); }
#pragma unroll
        for (int s = 0; s < GL; ++s) { float v = __uint_as_float(c1[s]); INS12G(v); }
        sGrp[t][0] = __float_as_uint(g0) & 0x3FF;
        sGrp[t][1] = __float_as_uint(g1) & 0x3FF;
        sGrp[t][2] = __float_as_uint(g2) & 0x3FF;
        sGrp[t][3] = __float_as_uint(g3) & 0x3FF;
        sGrp[t][4] = __float_as_uint(g4) & 0x3FF;
        sGrp[t][5] = __float_as_uint(g5) & 0x3FF;
        sGrp[t][6] = __float_as_uint(g6) & 0x3FF;
        sGrp[t][7] = __float_as_uint(g7) & 0x3FF;
        sGrp[t][8] = __float_as_uint(g8) & 0x3FF;
        sGrp[t][9] = __float_as_uint(g9) & 0x3FF;
        sGrp[t][10] = __float_as_uint(g10) & 0x3FF;
        sGrp[t][11] = __float_as_uint(g11) & 0x3FF;
    }
    __syncthreads();

    // 16 lanes per point: lane he<12 evaluates ONE group of 16 j exactly
    int hpt = t >> 4;       // 0..31 point within tile
    int he = t & 15;
    int hi = i0 + hpt;

    float xi[16];
    {
        const f32x4* xiv = (const f32x4*)(x + (size_t)hi * 16);
#pragma unroll
        for (int q = 0; q < 4; ++q) {
            f32x4 a = xiv[q];
#pragma unroll
            for (int r = 0; r < 4; ++r) xi[q * 4 + r] = a[r];
        }
    }

    float vv[16];
    int jbase = 0;
    float d0 = BIGF, d1 = BIGF, d2 = BIGF, d3 = BIGF;
    float d4 = BIGF, d5 = BIGF, d6 = BIGF, d7 = BIGF;
    if (he < GL) {
        int id = sGrp[hpt][he];
        jbase = ((id >> 9) & 1) * 8192 + ((id >> 1) & 7) * 1024 +
                ((id >> 4) & 31) * 32 + (id & 1) * 4;
#pragma unroll
        for (int r = 0; r < 16; ++r) {
            int j = jbase + (r & 3) + ((r >> 2) << 3);
            float dot = 0.0f;
            const f32x4* xjv = (const f32x4*)(x + (size_t)j * 16);
#pragma unroll
            for (int q = 0; q < 4; ++q) {
                f32x4 a = xjv[q];
                dot = fmaf(xi[q * 4 + 0], a[0], dot);
                dot = fmaf(xi[q * 4 + 1], a[1], dot);
                dot = fmaf(xi[q * 4 + 2], a[2], dot);
                dot = fmaf(xi[q * 4 + 3], a[3], dot);
            }
            float v = fmaf(dot, -2.0f, SQF[j]);
            vv[r] = v;
            INS8V(v);
        }
    } else {
#pragma unroll
        for (int r = 0; r < 16; ++r) vv[r] = BIGF;
    }

    MERGE8(1);
    MERGE8(2);
    MERGE8(4);
    MERGE8(8);
    float kth = d7;

    if (he < GL) {
#pragma unroll
        for (int r = 0; r < 16; ++r) {
            if (vv[r] <= kth) {
                int p = atomicAdd(&cnt[hpt], 1);
                if (p < KNN) sIdx[hpt * 8 + p] = jbase + (r & 3) + ((r >> 2) << 3);
            }
        }
    }
    __syncthreads();

    if (he < 8) {
        int e = he;
        int j = sIdx[hpt * 8 + e];

        float xd[16];
        {
            const f32x4* xjv = (const f32x4*)(x + (size_t)j * 16);
#pragma unroll
            for (int q = 0; q < 4; ++q) {
                f32x4 a = xjv[q];
#pragma unroll
                for (int r = 0; r < 4; ++r) xd[q * 4 + r] = a[r] - xi[q * 4 + r];
            }
        }

        float acc[16];
        {
            const f32x4* av = (const f32x4*)(ACC + (size_t)hi * 16);
#pragma unroll
            for (int q = 0; q < 4; ++q) {
                f32x4 a = av[q];
#pragma unroll
                for (int r = 0; r < 4; ++r) acc[q * 4 + r] = a[r];
            }
        }
#pragma unroll
        for (int d = 0; d < 16; ++d) {
            float v = xd[d];
#pragma unroll
            for (int h = 0; h < 16; ++h) acc[h] += v * sWe2[d * 16 + h];
        }

        float feats[16];
#pragma unroll
        for (int h = 0; h < 16; ++h) feats[h] = silu(acc[h]);

#pragma unroll
        for (int mask = 1; mask <= 4; mask <<= 1) {
#pragma unroll
            for (int h = 0; h < 16; ++h) feats[h] += __shfl_xor(feats[h], mask, 64);
        }
#pragma unroll
        for (int h = 0; h < 16; ++h) feats[h] *= 0.125f;

        float f1[32];
#pragma unroll
        for (int h = 0; h < 32; ++h) f1[h] = sbf1[h];
#pragma unroll
        for (int k = 0; k < 16; ++k) {
            float v = feats[k];
#pragma unroll
            for (int h = 0; h < 32; ++h) f1[h] += v * sWf1[k * 32 + h];
        }
#pragma unroll
        for (int h = 0; h < 32; ++h) f1[h] = silu(f1[h]);

        float f2[16];
#pragma unroll
        for (int h = 0; h < 16; ++h) f2[h] = sbf2[h];
#pragma unroll
        for (int k = 0; k < 32; ++k) {
            float v = f1[k];
#pragma unroll
            for (int h = 0; h < 16; ++h) f2[h] += v * sWf2[k * 16 + h];
        }

        if (e < 4) {
#pragma unroll
            for (int q = 0; q < 4; ++q)
                out[(size_t)hi * 29 + e * 4 + q] = f2[e * 4 + q];
        } else {
            int d00 = (e - 4) * 4;
#pragma unroll
            for (int q = 0; q < 4; ++q) {
                int d = d00 + q;
                if (d < DIN) out[(size_t)hi * 29 + 16 + d] = x_pfc[hi * DIN + d];
            }
        }
    }
}

extern "C" void kernel_launch(void* const* d_in, const int* in_sizes, int n_in,
                              void* d_out, int out_size, void* d_ws, size_t ws_size,
                              hipStream_t stream)
{
    const float* x_pfc = (const float*)d_in[0];
    const float* W1 = (const float*)d_in[1];
    const float* b1 = (const float*)d_in[2];
    const float* W2 = (const float*)d_in[3];
    const float* b2 = (const float*)d_in[4];
    const float* W3 = (const float*)d_in[5];
    const float* b3 = (const float*)d_in[6];
    const float* We = (const float*)d_in[7];
    const float* be = (const float*)d_in[8];
    const float* Wf1 = (const float*)d_in[9];
    const float* bf1 = (const float*)d_in[10];
    const float* Wf2 = (const float*)d_in[11];
    const float* bf2 = (const float*)d_in[12];
    float* out = (float*)d_out;

    float* xw = (float*)d_ws;                         // N*16 f32
    float* ACCa = xw + (size_t)NPTS * 16;             // N*16 f32
    _Float16* Ha = (_Float16*)(ACCa + (size_t)NPTS * 16);  // N*16 f16
    _Float16* La = Ha + (size_t)NPTS * 16;
    _Float16* YHa = La + (size_t)NPTS * 16;
    _Float16* YLa = YHa + (size_t)NPTS * 16;
    float* SQFa = (float*)(YLa + (size_t)NPTS * 16);  // N f32
    float* SQPa = SQFa + NPTS;                        // N f32 (permuted)
    unsigned* CVa = (unsigned*)(SQPa + NPTS);         // 2*N*GL u32
    unsigned* tick = CVa + (size_t)2 * NPTS * GL;     // 512 u32

    hipLaunchKernelGGL(k_encoder, dim3(NPTS / 64), dim3(64), 0, stream,
                       x_pfc, W1, b1, W2, b2, W3, b3, We, be,
                       xw, Ha, La, YHa, YLa, SQFa, SQPa, ACCa);
    hipLaunchKernelGGL(k_knn, dim3(NPTS / 32 * 2), dim3(512), 0, stream,
                       Ha, La, YHa, YLa, SQPa, CVa, tick,
                       xw, SQFa, x_pfc, ACCa, We, Wf1, bf1, Wf2, bf2, out);
}

// Round 16
// 180.164 us; speedup vs baseline: 3.0215x; 3.0215x over previous
//
#include <hip/hip_runtime.h>
#include <math.h>

#define NPTS 16384
#define DIN 13
#define KNN 8
#define GL 12                 // group-list depth
#define BIGF 1.7014118e38f    // 0x7F000000 — finite sentinel, id bits 0

typedef _Float16 half8 __attribute__((ext_vector_type(8)));
typedef float f32x4 __attribute__((ext_vector_type(4)));
typedef float f32x16 __attribute__((ext_vector_type(16)));

union HU4 { uint4 u; half8 h; };

__device__ __forceinline__ float silu(float v) {
    return v / (1.0f + __expf(-v));
}

#define MED3(v, a, b) __builtin_amdgcn_fmed3f((v), (a), (b))

#define INS8V(v) {                      \
    d7 = MED3((v), d6, d7);             \
    d6 = MED3((v), d5, d6);             \
    d5 = MED3((v), d4, d5);             \
    d4 = MED3((v), d3, d4);             \
    d3 = MED3((v), d2, d3);             \
    d2 = MED3((v), d1, d2);             \
    d1 = MED3((v), d0, d1);             \
    d0 = fminf((v), d0); }

#define INS12G(v) {                     \
    g11 = MED3((v), g10, g11);          \
    g10 = MED3((v), g9, g10);           \
    g9  = MED3((v), g8, g9);            \
    g8  = MED3((v), g7, g8);            \
    g7  = MED3((v), g6, g7);            \
    g6  = MED3((v), g5, g6);            \
    g5  = MED3((v), g4, g5);            \
    g4  = MED3((v), g3, g4);            \
    g3  = MED3((v), g2, g3);            \
    g2  = MED3((v), g1, g2);            \
    g1  = MED3((v), g0, g1);            \
    g0  = fminf((v), g0); }

#define CSW(p, q) { float lo_ = fminf(m##p, m##q); float hi_ = fmaxf(m##p, m##q); m##p = lo_; m##q = hi_; }

#define CLEAN16() \
    CSW(0,8) CSW(1,9) CSW(2,10) CSW(3,11) CSW(4,12) CSW(5,13) CSW(6,14) CSW(7,15) \
    CSW(0,4) CSW(1,5) CSW(2,6) CSW(3,7) CSW(8,12) CSW(9,13) CSW(10,14) CSW(11,15) \
    CSW(0,2) CSW(1,3) CSW(4,6) CSW(5,7) CSW(8,10) CSW(9,11) CSW(12,14) CSW(13,15) \
    CSW(0,1) CSW(2,3) CSW(4,5) CSW(6,7) CSW(8,9) CSW(10,11) CSW(12,13) CSW(14,15)

#define MERGE12_SHFL(mask) {                                  \
    float b0 = __shfl_xor(g0, (mask), 64);                    \
    float b1 = __shfl_xor(g1, (mask), 64);                    \
    float b2 = __shfl_xor(g2, (mask), 64);                    \
    float b3 = __shfl_xor(g3, (mask), 64);                    \
    float b4 = __shfl_xor(g4, (mask), 64);                    \
    float b5 = __shfl_xor(g5, (mask), 64);                    \
    float b6 = __shfl_xor(g6, (mask), 64);                    \
    float b7 = __shfl_xor(g7, (mask), 64);                    \
    float b8 = __shfl_xor(g8, (mask), 64);                    \
    float b9 = __shfl_xor(g9, (mask), 64);                    \
    float b10 = __shfl_xor(g10, (mask), 64);                  \
    float b11 = __shfl_xor(g11, (mask), 64);                  \
    float m0 = g0, m1 = g1, m2 = g2, m3 = g3;                 \
    float m4 = fminf(g4, b11), m5 = fminf(g5, b10);           \
    float m6 = fminf(g6, b9),  m7 = fminf(g7, b8);            \
    float m8 = fminf(g8, b7),  m9 = fminf(g9, b6);            \
    float m10 = fminf(g10, b5), m11 = fminf(g11, b4);         \
    float m12 = b3, m13 = b2, m14 = b1, m15 = b0;             \
    CLEAN16();                                                \
    g0 = m0; g1 = m1; g2 = m2; g3 = m3; g4 = m4; g5 = m5;     \
    g6 = m6; g7 = m7; g8 = m8; g9 = m9; g10 = m10; g11 = m11; }

#define MERGE12_LDS(LD) {                                     \
    float b0 = LD(0), b1 = LD(1), b2 = LD(2), b3 = LD(3);     \
    float b4 = LD(4), b5 = LD(5), b6 = LD(6), b7 = LD(7);     \
    float b8 = LD(8), b9 = LD(9), b10 = LD(10), b11 = LD(11); \
    float m0 = g0, m1 = g1, m2 = g2, m3 = g3;                 \
    float m4 = fminf(g4, b11), m5 = fminf(g5, b10);           \
    float m6 = fminf(g6, b9),  m7 = fminf(g7, b8);            \
    float m8 = fminf(g8, b7),  m9 = fminf(g9, b6);            \
    float m10 = fminf(g10, b5), m11 = fminf(g11, b4);         \
    float m12 = b3, m13 = b2, m14 = b1, m15 = b0;             \
    CLEAN16();                                                \
    g0 = m0; g1 = m1; g2 = m2; g3 = m3; g4 = m4; g5 = m5;     \
    g6 = m6; g7 = m7; g8 = m8; g9 = m9; g10 = m10; g11 = m11; }

#define MERGE8(mask) {                                   \
    float b0 = __shfl_xor(d0, (mask), 64);               \
    float b1 = __shfl_xor(d1, (mask), 64);               \
    float b2 = __shfl_xor(d2, (mask), 64);               \
    float b3 = __shfl_xor(d3, (mask), 64);               \
    float b4 = __shfl_xor(d4, (mask), 64);               \
    float b5 = __shfl_xor(d5, (mask), 64);               \
    float b6 = __shfl_xor(d6, (mask), 64);               \
    float b7 = __shfl_xor(d7, (mask), 64);               \
    float m0 = fminf(d0, b7), m1 = fminf(d1, b6);        \
    float m2 = fminf(d2, b5), m3 = fminf(d3, b4);        \
    float m4 = fminf(d4, b3), m5 = fminf(d5, b2);        \
    float m6 = fminf(d6, b1), m7 = fminf(d7, b0);        \
    CSW(0,4) CSW(1,5) CSW(2,6) CSW(3,7)                  \
    CSW(0,2) CSW(1,3) CSW(4,6) CSW(5,7)                  \
    CSW(0,1) CSW(2,3) CSW(4,5) CSW(6,7)                  \
    d0 = m0; d1 = m1; d2 = m2; d3 = m3;                  \
    d4 = m4; d5 = m5; d6 = m6; d7 = m7; }

// ---- K1: encoder MLP -> x, H/L/YH/YL f16 splits, SQF, packed SQHL, ACC ----
__global__ __launch_bounds__(64) void k_encoder(
    const float* __restrict__ x_pfc,
    const float* __restrict__ W1, const float* __restrict__ b1,
    const float* __restrict__ W2, const float* __restrict__ b2,
    const float* __restrict__ W3, const float* __restrict__ b3,
    const float* __restrict__ We, const float* __restrict__ be,
    float* __restrict__ xo, _Float16* __restrict__ H, _Float16* __restrict__ L,
    _Float16* __restrict__ YH, _Float16* __restrict__ YL,
    float* __restrict__ SQF, unsigned* __restrict__ SQHL,
    float* __restrict__ ACC)
{
    __shared__ float sW1[DIN * 8];
    __shared__ float sb1[8];
    __shared__ float sW2[8 * 16];
    __shared__ float sb2[16];
    __shared__ float sW3[16 * 15];
    __shared__ float sb3[15];
    __shared__ float sWe[16 * 16];
    __shared__ float sbe[16];
    int t = threadIdx.x;
    for (int q = t; q < DIN * 8; q += 64) sW1[q] = W1[q];
    for (int q = t; q < 8; q += 64) sb1[q] = b1[q];
    for (int q = t; q < 8 * 16; q += 64) sW2[q] = W2[q];
    for (int q = t; q < 16; q += 64) sb2[q] = b2[q];
    for (int q = t; q < 16 * 15; q += 64) sW3[q] = W3[q];
    for (int q = t; q < 15; q += 64) sb3[q] = b3[q];
    for (int q = t; q < 16 * 16; q += 64) sWe[q] = We[q];
    for (int q = t; q < 16; q += 64) sbe[q] = be[q];
    __syncthreads();

    int i = blockIdx.x * 64 + t;
    float in[DIN];
#pragma unroll
    for (int d = 0; d < DIN; ++d) in[d] = x_pfc[i * DIN + d];

    float a1[8];
#pragma unroll
    for (int h = 0; h < 8; ++h) a1[h] = sb1[h];
#pragma unroll
    for (int d = 0; d < DIN; ++d) {
        float v = in[d];
#pragma unroll
        for (int h = 0; h < 8; ++h) a1[h] += v * sW1[d * 8 + h];
    }
#pragma unroll
    for (int h = 0; h < 8; ++h) a1[h] = silu(a1[h]);

    float a2[16];
#pragma unroll
    for (int h = 0; h < 16; ++h) a2[h] = sb2[h];
#pragma unroll
    for (int d = 0; d < 8; ++d) {
        float v = a1[d];
#pragma unroll
        for (int h = 0; h < 16; ++h) a2[h] += v * sW2[d * 16 + h];
    }
#pragma unroll
    for (int h = 0; h < 16; ++h) a2[h] = silu(a2[h]);

    float a3[15];
#pragma unroll
    for (int h = 0; h < 15; ++h) a3[h] = sb3[h];
#pragma unroll
    for (int d = 0; d < 16; ++d) {
        float v = a2[d];
#pragma unroll
        for (int h = 0; h < 15; ++h) a3[h] += v * sW3[d * 15 + h];
    }

    float xr[16];
#pragma unroll
    for (int h = 0; h < 15; ++h) xr[h] = a3[h];
    xr[15] = in[DIN - 1];

    float s = 0.0f;
#pragma unroll
    for (int d = 0; d < 16; ++d) s += xr[d] * xr[d];

    float accb[16];
#pragma unroll
    for (int h = 0; h < 16; ++h) accb[h] = sbe[h];
#pragma unroll
    for (int d = 0; d < 16; ++d) {
        float v = xr[d];
#pragma unroll
        for (int h = 0; h < 16; ++h) accb[h] += v * sWe[d * 16 + h];
    }

    _Float16 hb[16], lb[16], yhb[16], ylb[16];
#pragma unroll
    for (int d = 0; d < 16; ++d) {
        _Float16 h = (_Float16)xr[d];
        hb[d] = h;
        lb[d] = (_Float16)(xr[d] - (float)h);
        float y = -2.0f * xr[d];
        _Float16 yh = (_Float16)y;
        yhb[d] = yh;
        ylb[d] = (_Float16)(y - (float)yh);
    }
    {
        uint4* p;
        p = (uint4*)(H + (size_t)i * 16);  p[0] = ((uint4*)hb)[0];  p[1] = ((uint4*)hb)[1];
        p = (uint4*)(L + (size_t)i * 16);  p[0] = ((uint4*)lb)[0];  p[1] = ((uint4*)lb)[1];
        p = (uint4*)(YH + (size_t)i * 16); p[0] = ((uint4*)yhb)[0]; p[1] = ((uint4*)yhb)[1];
        p = (uint4*)(YL + (size_t)i * 16); p[0] = ((uint4*)ylb)[0]; p[1] = ((uint4*)ylb)[1];
        f32x4* xq = (f32x4*)(xo + (size_t)i * 16);
        f32x4* aq = (f32x4*)(ACC + (size_t)i * 16);
#pragma unroll
        for (int q = 0; q < 4; ++q) {
            f32x4 xv, av;
#pragma unroll
            for (int r = 0; r < 4; ++r) { xv[r] = xr[q * 4 + r]; av[r] = accb[q * 4 + r]; }
            xq[q] = xv;
            aq[q] = av;
        }
    }
    SQF[i] = s;
    {
        // packed f16 hi/lo split of sq: low16 = sqh, high16 = sql
        _Float16 sh = (_Float16)s;
        _Float16 sl = (_Float16)(s - (float)sh);
        unsigned uh = *(const unsigned short*)&sh;
        unsigned ul = *(const unsigned short*)&sl;
        SQHL[i] = (ul << 16) | uh;
    }
}

// ---- K2: MFMA 32x32 KNN, single pass, sq folded into MFMA ----
// Grid 1024 = 512 i-tiles x 2 j-halves, 8 waves. Per 32-j tile:
//   C = A4.B4 + Ah.B1 + Al.B1 + Ah.B2  (4x mfma_32x32x16, fp32 acc, c0=0)
// where A4 = [sqh,sql,0..] (hh=0 lanes), B4 = [1,1,0..] (hh=0 lanes)
//   -> C = sq_j - 2 x_i.x_j. One 4B SQHL dword/lane/tile replaces the 64B
// f32x16 c-init load (kills ~1 GB of L2 sq traffic).
// Selection: packed quad... group-min (lane's 16 C values) into sorted-12,
// id in low 10 mantissa bits; merge hh (shfl) + waves (LDS tree).
__global__ __launch_bounds__(512, 8) void k_knn(
    const _Float16* __restrict__ H, const _Float16* __restrict__ L,
    const _Float16* __restrict__ YH, const _Float16* __restrict__ YL,
    const unsigned* __restrict__ SQHL, unsigned* __restrict__ CV)
{
    __shared__ float wl[8 * GL * 32];   // 12 KB

    int t = threadIdx.x;
    int w = t >> 6;
    int lane = t & 63;
    int r31 = lane & 31;
    int hh = lane >> 5;
    int ih = blockIdx.x >> 1;
    int jh = blockIdx.x & 1;
    int i0 = ih * 32;

    int gi = i0 + r31;
    half8 B1 = *(const half8*)(YH + (size_t)gi * 16 + hh * 8);
    half8 B2 = *(const half8*)(YL + (size_t)gi * 16 + hh * 8);
    half8 B4;
    {
        HU4 r;
        r.u.x = (hh == 0) ? 0x3C003C00u : 0u;   // (1.0h, 1.0h) at k=0,1
        r.u.y = 0u; r.u.z = 0u; r.u.w = 0u;
        B4 = r.h;
    }

    float g0 = BIGF, g1 = BIGF, g2 = BIGF, g3 = BIGF;
    float g4 = BIGF, g5 = BIGF, g6 = BIGF, g7 = BIGF;
    float g8 = BIGF, g9 = BIGF, g10 = BIGF, g11 = BIGF;

    int jw = jh * 8192 + w * 1024;
    const _Float16* pH = H + ((size_t)(jw + r31)) * 16 + hh * 8;
    const _Float16* pL = L + ((size_t)(jw + r31)) * 16 + hh * 8;
    const unsigned* pQ = SQHL + jw + r31;
    unsigned idt = (unsigned)((w << 1) | hh);

    for (int tt = 0; tt < 32; ++tt) {
        half8 Ah = *(const half8*)pH;
        half8 Al = *(const half8*)pL;
        unsigned squ = *pQ;
        HU4 a4;
        a4.u.x = (hh == 0) ? squ : 0u;   // (sqh, sql) at k=0,1
        a4.u.y = 0u; a4.u.z = 0u; a4.u.w = 0u;

        f32x16 c = {};
        c = __builtin_amdgcn_mfma_f32_32x32x16_f16(a4.h, B4, c, 0, 0, 0);
        c = __builtin_amdgcn_mfma_f32_32x32x16_f16(Ah, B1, c, 0, 0, 0);
        c = __builtin_amdgcn_mfma_f32_32x32x16_f16(Al, B1, c, 0, 0, 0);
        c = __builtin_amdgcn_mfma_f32_32x32x16_f16(Ah, B2, c, 0, 0, 0);

        float t01 = fminf(c[0], c[1]),  t23 = fminf(c[2], c[3]);
        float t45 = fminf(c[4], c[5]),  t67 = fminf(c[6], c[7]);
        float t89 = fminf(c[8], c[9]),  tAB = fminf(c[10], c[11]);
        float tCD = fminf(c[12], c[13]), tEF = fminf(c[14], c[15]);
        float q0 = fminf(t01, t23), q1 = fminf(t45, t67);
        float q2 = fminf(t89, tAB), q3 = fminf(tCD, tEF);
        float vmin = fminf(fminf(q0, q1), fminf(q2, q3));

        unsigned pk = (__float_as_uint(vmin) & 0xFFFFFC00u) | idt;
        float pf = __uint_as_float(pk);
        INS12G(pf);

        idt += 16;
        pH += 32 * 16;
        pL += 32 * 16;
        pQ += 32;
    }

    MERGE12_SHFL(32);

#define STORE12() if (lane < 32) {                     \
        wl[(w * GL + 0) * 32 + r31] = g0;              \
        wl[(w * GL + 1) * 32 + r31] = g1;              \
        wl[(w * GL + 2) * 32 + r31] = g2;              \
        wl[(w * GL + 3) * 32 + r31] = g3;              \
        wl[(w * GL + 4) * 32 + r31] = g4;              \
        wl[(w * GL + 5) * 32 + r31] = g5;              \
        wl[(w * GL + 6) * 32 + r31] = g6;              \
        wl[(w * GL + 7) * 32 + r31] = g7;              \
        wl[(w * GL + 8) * 32 + r31] = g8;              \
        wl[(w * GL + 9) * 32 + r31] = g9;              \
        wl[(w * GL + 10) * 32 + r31] = g10;            \
        wl[(w * GL + 11) * 32 + r31] = g11; }

    if (w >= 4) STORE12();
    __syncthreads();
    if (w < 4) {
        int pw = w + 4;
#define LD(s) wl[(pw * GL + (s)) * 32 + r31]
        MERGE12_LDS(LD);
#undef LD
    }
    __syncthreads();
    if (w == 2 || w == 3) STORE12();
    __syncthreads();
    if (w < 2) {
        int pw = w + 2;
#define LD(s) wl[(pw * GL + (s)) * 32 + r31]
        MERGE12_LDS(LD);
#undef LD
    }
    __syncthreads();
    if (w == 1) STORE12();
    __syncthreads();
    if (w == 0) {
        int pw = 1;
#define LD(s) wl[(pw * GL + (s)) * 32 + r31]
        MERGE12_LDS(LD);
#undef LD
        if (lane < 32) {
            unsigned jb = ((unsigned)jh) << 9;
            size_t base = ((size_t)jh * NPTS + (i0 + r31)) * GL;
            CV[base + 0] = __float_as_uint(g0) | jb;
            CV[base + 1] = __float_as_uint(g1) | jb;
            CV[base + 2] = __float_as_uint(g2) | jb;
            CV[base + 3] = __float_as_uint(g3) | jb;
            CV[base + 4] = __float_as_uint(g4) | jb;
            CV[base + 5] = __float_as_uint(g5) | jb;
            CV[base + 6] = __float_as_uint(g6) | jb;
            CV[base + 7] = __float_as_uint(g7) | jb;
            CV[base + 8] = __float_as_uint(g8) | jb;
            CV[base + 9] = __float_as_uint(g9) | jb;
            CV[base + 10] = __float_as_uint(g10) | jb;
            CV[base + 11] = __float_as_uint(g11) | jb;
        }
    }
#undef STORE12
}

// ---- K3: group re-eval + exact top-8 + edge conv + head MLP ----
// (unchanged from round 12 — best-known config)
__global__ __launch_bounds__(256) void k_head(
    const float* __restrict__ x, const unsigned* __restrict__ CV,
    const float* __restrict__ SQF,
    const float* __restrict__ x_pfc, const float* __restrict__ ACC,
    const float* __restrict__ We,
    const float* __restrict__ Wf1, const float* __restrict__ bf1,
    const float* __restrict__ Wf2, const float* __restrict__ bf2,
    float* __restrict__ out)
{
    __shared__ float sWe2[16 * 16];
    __shared__ float sWf1[16 * 32];
    __shared__ float sbf1[32];
    __shared__ float sWf2[32 * 16];
    __shared__ float sbf2[16];
    __shared__ int sGrp[32][GL];
    __shared__ float vals[32 * 256];   // 32 KB
    __shared__ int cnt[32];
    __shared__ int sIdx[32 * 8];
    int t = threadIdx.x;
    for (int q = t; q < 16 * 16; q += 256) sWe2[q] = We[256 + q];
    for (int q = t; q < 16 * 32; q += 256) sWf1[q] = Wf1[q];
    for (int q = t; q < 32; q += 256) sbf1[q] = bf1[q];
    for (int q = t; q < 32 * 16; q += 256) sWf2[q] = Wf2[q];
    for (int q = t; q < 16; q += 256) sbf2[q] = bf2[q];

    int i0 = blockIdx.x * 32;

    if (t < 32) {
        int i = i0 + t;
        cnt[t] = 0;
        float g0 = BIGF, g1 = BIGF, g2 = BIGF, g3 = BIGF;
        float g4 = BIGF, g5 = BIGF, g6 = BIGF, g7 = BIGF;
        float g8 = BIGF, g9 = BIGF, g10 = BIGF, g11 = BIGF;
        const unsigned* c0 = CV + (size_t)i * GL;
        const unsigned* c1 = CV + ((size_t)NPTS + i) * GL;
#pragma unroll
        for (int s = 0; s < GL; ++s) { float v = __uint_as_float(c0[s]); INS12G(v); }
#pragma unroll
        for (int s = 0; s < GL; ++s) { float v = __uint_as_float(c1[s]); INS12G(v); }
        sGrp[t][0] = __float_as_uint(g0) & 0x3FF;
        sGrp[t][1] = __float_as_uint(g1) & 0x3FF;
        sGrp[t][2] = __float_as_uint(g2) & 0x3FF;
        sGrp[t][3] = __float_as_uint(g3) & 0x3FF;
        sGrp[t][4] = __float_as_uint(g4) & 0x3FF;
        sGrp[t][5] = __float_as_uint(g5) & 0x3FF;
        sGrp[t][6] = __float_as_uint(g6) & 0x3FF;
        sGrp[t][7] = __float_as_uint(g7) & 0x3FF;
        sGrp[t][8] = __float_as_uint(g8) & 0x3FF;
        sGrp[t][9] = __float_as_uint(g9) & 0x3FF;
        sGrp[t][10] = __float_as_uint(g10) & 0x3FF;
        sGrp[t][11] = __float_as_uint(g11) & 0x3FF;
    }
    __syncthreads();

    int pt = t >> 3;
    int e = t & 7;
    int i = i0 + pt;

    float xi[16];
    {
        const f32x4* xiv = (const f32x4*)(x + (size_t)i * 16);
#pragma unroll
        for (int q = 0; q < 4; ++q) {
            f32x4 a = xiv[q];
#pragma unroll
            for (int r = 0; r < 4; ++r) xi[q * 4 + r] = a[r];
        }
    }

    // scan A: evaluate candidates, store values, per-lane top-8
    float d0 = BIGF, d1 = BIGF, d2 = BIGF, d3 = BIGF;
    float d4 = BIGF, d5 = BIGF, d6 = BIGF, d7 = BIGF;
#pragma unroll
    for (int s2 = 0; s2 < 2; ++s2) {
        int gidx = e * 2 + s2;
        if (gidx < GL) {
            int id = sGrp[pt][gidx];
            int jb = ((id >> 9) & 1) * 8192 + ((id >> 1) & 7) * 1024 +
                     ((id >> 4) & 31) * 32 + (id & 1) * 4;
#pragma unroll
            for (int r = 0; r < 16; ++r) {
                int j = jb + (r & 3) + ((r >> 2) << 3);
                float dot = 0.0f;
                const f32x4* xjv = (const f32x4*)(x + (size_t)j * 16);
#pragma unroll
                for (int q = 0; q < 4; ++q) {
                    f32x4 a = xjv[q];
                    dot = fmaf(xi[q * 4 + 0], a[0], dot);
                    dot = fmaf(xi[q * 4 + 1], a[1], dot);
                    dot = fmaf(xi[q * 4 + 2], a[2], dot);
                    dot = fmaf(xi[q * 4 + 3], a[3], dot);
                }
                float v = fmaf(dot, -2.0f, SQF[j]);
                vals[pt * 256 + gidx * 16 + r] = v;
                INS8V(v);
            }
        } else {
#pragma unroll
            for (int r = 0; r < 16; ++r)
                vals[pt * 256 + gidx * 16 + r] = BIGF;
        }
    }

    // exact kth over the point's candidates (8-lane butterfly)
    MERGE8(1);
    MERGE8(2);
    MERGE8(4);
    float kth = d7;

    // scan B: deterministic re-read, collect ids
#pragma unroll
    for (int s2 = 0; s2 < 2; ++s2) {
        int gidx = e * 2 + s2;
        int id = (gidx < GL) ? sGrp[pt][gidx] : 0;
        int jb = ((id >> 9) & 1) * 8192 + ((id >> 1) & 7) * 1024 +
                 ((id >> 4) & 31) * 32 + (id & 1) * 4;
#pragma unroll
        for (int r = 0; r < 16; ++r) {
            float v = vals[pt * 256 + gidx * 16 + r];
            if (v <= kth) {
                int j = jb + (r & 3) + ((r >> 2) << 3);
                int p = atomicAdd(&cnt[pt], 1);
                if (p < KNN) sIdx[pt * 8 + p] = j;
            }
        }
    }
    __syncthreads();

    int j = sIdx[pt * 8 + e];

    float xd[16];
    {
        const f32x4* xjv = (const f32x4*)(x + (size_t)j * 16);
#pragma unroll
        for (int q = 0; q < 4; ++q) {
            f32x4 a = xjv[q];
#pragma unroll
            for (int r = 0; r < 4; ++r) xd[q * 4 + r] = a[r] - xi[q * 4 + r];
        }
    }

    float acc[16];
    {
        const f32x4* av = (const f32x4*)(ACC + (size_t)i * 16);
#pragma unroll
        for (int q = 0; q < 4; ++q) {
            f32x4 a = av[q];
#pragma unroll
            for (int r = 0; r < 4; ++r) acc[q * 4 + r] = a[r];
        }
    }
#pragma unroll
    for (int d = 0; d < 16; ++d) {
        float v = xd[d];
#pragma unroll
        for (int h = 0; h < 16; ++h) acc[h] += v * sWe2[d * 16 + h];
    }

    float feats[16];
#pragma unroll
    for (int h = 0; h < 16; ++h) feats[h] = silu(acc[h]);

#pragma unroll
    for (int mask = 1; mask <= 4; mask <<= 1) {
#pragma unroll
        for (int h = 0; h < 16; ++h) feats[h] += __shfl_xor(feats[h], mask, 64);
    }
#pragma unroll
    for (int h = 0; h < 16; ++h) feats[h] *= 0.125f;

    float f1[32];
#pragma unroll
    for (int h = 0; h < 32; ++h) f1[h] = sbf1[h];
#pragma unroll
    for (int k = 0; k < 16; ++k) {
        float v = feats[k];
#pragma unroll
        for (int h = 0; h < 32; ++h) f1[h] += v * sWf1[k * 32 + h];
    }
#pragma unroll
    for (int h = 0; h < 32; ++h) f1[h] = silu(f1[h]);

    float f2[16];
#pragma unroll
    for (int h = 0; h < 16; ++h) f2[h] = sbf2[h];
#pragma unroll
    for (int k = 0; k < 32; ++k) {
        float v = f1[k];
#pragma unroll
        for (int h = 0; h < 16; ++h) f2[h] += v * sWf2[k * 16 + h];
    }

    if (e < 4) {
#pragma unroll
        for (int q = 0; q < 4; ++q)
            out[(size_t)i * 29 + e * 4 + q] = f2[e * 4 + q];
    } else {
        int d00 = (e - 4) * 4;
#pragma unroll
        for (int q = 0; q < 4; ++q) {
            int d = d00 + q;
            if (d < DIN) out[(size_t)i * 29 + 16 + d] = x_pfc[i * DIN + d];
        }
    }
}

extern "C" void kernel_launch(void* const* d_in, const int* in_sizes, int n_in,
                              void* d_out, int out_size, void* d_ws, size_t ws_size,
                              hipStream_t stream)
{
    const float* x_pfc = (const float*)d_in[0];
    const float* W1 = (const float*)d_in[1];
    const float* b1 = (const float*)d_in[2];
    const float* W2 = (const float*)d_in[3];
    const float* b2 = (const float*)d_in[4];
    const float* W3 = (const float*)d_in[5];
    const float* b3 = (const float*)d_in[6];
    const float* We = (const float*)d_in[7];
    const float* be = (const float*)d_in[8];
    const float* Wf1 = (const float*)d_in[9];
    const float* bf1 = (const float*)d_in[10];
    const float* Wf2 = (const float*)d_in[11];
    const float* bf2 = (const float*)d_in[12];
    float* out = (float*)d_out;

    float* xw = (float*)d_ws;                         // N*16 f32
    float* ACCa = xw + (size_t)NPTS * 16;             // N*16 f32
    _Float16* Ha = (_Float16*)(ACCa + (size_t)NPTS * 16);  // N*16 f16
    _Float16* La = Ha + (size_t)NPTS * 16;
    _Float16* YHa = La + (size_t)NPTS * 16;
    _Float16* YLa = YHa + (size_t)NPTS * 16;
    float* SQFa = (float*)(YLa + (size_t)NPTS * 16);  // N f32
    unsigned* SQHLa = (unsigned*)(SQFa + NPTS);       // N u32 (packed f16 split)
    unsigned* CVa = SQHLa + NPTS;                     // 2*N*GL u32

    hipLaunchKernelGGL(k_encoder, dim3(NPTS / 64), dim3(64), 0, stream,
                       x_pfc, W1, b1, W2, b2, W3, b3, We, be,
                       xw, Ha, La, YHa, YLa, SQFa, SQHLa, ACCa);
    hipLaunchKernelGGL(k_knn, dim3(NPTS / 32 * 2), dim3(512), 0, stream,
                       Ha, La, YHa, YLa, SQHLa, CVa);
    hipLaunchKernelGGL(k_head, dim3(NPTS / 32), dim3(256), 0, stream,
                       xw, CVa, SQFa, x_pfc, ACCa, We, Wf1, bf1, Wf2, bf2, out);
}